// Round 2
// baseline (333.837 us; speedup 1.0000x reference)
//
#include <hip/hip_runtime.h>
#include <math.h>

typedef unsigned short u16;
typedef unsigned int u32;
typedef __attribute__((ext_vector_type(8))) __bf16 bf16x8;
typedef __attribute__((ext_vector_type(8))) u16 u16x8;
typedef __attribute__((ext_vector_type(4))) u16 u16x4;
typedef __attribute__((ext_vector_type(4))) float f32x4;

#define GLOAD16(gp, lp)                                                        \
  __builtin_amdgcn_global_load_lds(                                            \
      (const __attribute__((address_space(1))) unsigned int*)(gp),             \
      (__attribute__((address_space(3))) unsigned int*)(lp), 16, 0, 0)

#define LOG2E 1.4426950408889634f

__device__ __forceinline__ u16 bf16r(float f) {
  unsigned u = __float_as_uint(f);
  u += 0x7fff + ((u >> 16) & 1);
  return (u16)(u >> 16);
}

__device__ __forceinline__ float bf2f(u16 v) {
  return __uint_as_float(((u32)v) << 16);
}

__device__ __forceinline__ bf16x8 ldfrag(const u16* p) {
  return __builtin_bit_cast(bf16x8, *(const u16x8*)p);
}

__device__ __forceinline__ f32x4 mfma16(bf16x8 a, bf16x8 b, f32x4 c) {
  return __builtin_amdgcn_mfma_f32_16x16x32_bf16(a, b, c, 0, 0, 0);
}

__device__ __forceinline__ float fast_exp2(float x) {
  float r;
  asm("v_exp_f32 %0, %1" : "=v"(r) : "v"(x));
  return r;
}

// ---------------- constants ----------------
// B=2 S=2048 D_MODEL=1024 H=16 DKV=64, inner=1024
#define QKV_MAT_STRIDE (2 * 16 * 2048 * 64)  // elements per one of q/k/v

// ---------------- LUT: T5 relative bucket of rel in [-4096,4096] -----------
__global__ void k_build_lut(signed char* __restrict__ lut8) {
  int i = blockIdx.x * 256 + threadIdx.x;
  if (i > 8192) return;
  int rel = i - 4096;
  int ret = rel > 0 ? 16 : 0;
  int n = rel < 0 ? -rel : rel;
  int bucket;
  if (n < 8) {
    bucket = n;
  } else {
    int vl = 8 + (int)(log((double)n / 8.0) / log(16.0) * 8.0);
    bucket = vl > 15 ? 15 : vl;
  }
  lut8[i] = (signed char)(ret + bucket);
}

// ---------------- per-key bias (pre-scaled by log2e) ----------------------
__global__ void k_kbias(const float* __restrict__ mask, const float* __restrict__ ss,
                        const int* __restrict__ nd, float* __restrict__ kb) {
  int i = blockIdx.x * 256 + threadIdx.x;  // < 4096
  kb[i] = (-1000.0f * (1.0f - mask[i]) + logf(ss[i] + 1e-4f) +
           logf((float)nd[i] + 1e-4f)) * LOG2E;
}

// ---------------- weight transpose fp32 [k][n] -> bf16 [n][k] --------------
__global__ __launch_bounds__(256) void k_transpose(
    const float* __restrict__ Wq, const float* __restrict__ Wk,
    const float* __restrict__ Wv, const float* __restrict__ Wo,
    u16* __restrict__ wtqkv, u16* __restrict__ wto) {
  int z = blockIdx.z;
  const float* W = (z == 0) ? Wq : (z == 1) ? Wk : (z == 2) ? Wv : Wo;
  u16* Wt = (z < 3) ? (wtqkv + (size_t)z * 1024 * 1024) : wto;
  __shared__ float tile[32][33];
  int n0 = blockIdx.x * 32, k0 = blockIdx.y * 32;
  int tx = threadIdx.x, ty = threadIdx.y;  // (32,8)
#pragma unroll
  for (int j = 0; j < 4; ++j)
    tile[ty + 8 * j][tx] = W[(size_t)(k0 + ty + 8 * j) * 1024 + n0 + tx];
  __syncthreads();
#pragma unroll
  for (int j = 0; j < 4; ++j)
    Wt[(size_t)(n0 + ty + 8 * j) * 1024 + k0 + tx] = bf16r(tile[tx][ty + 8 * j]);
}

// ---------------- RMSNorm (T5 LayerNorm) -> bf16 --------------------------
__global__ __launch_bounds__(256) void k_rmsnorm(const float* __restrict__ x,
                                                 const float* __restrict__ w,
                                                 u16* __restrict__ out) {
  int row = blockIdx.x;  // 0..4095
  int t = threadIdx.x;
  const float4 v = ((const float4*)(x + (size_t)row * 1024))[t];
  float ss = v.x * v.x + v.y * v.y + v.z * v.z + v.w * v.w;
#pragma unroll
  for (int o = 1; o < 64; o <<= 1) ss += __shfl_xor(ss, o);
  __shared__ float wsum[4];
  if ((t & 63) == 0) wsum[t >> 6] = ss;
  __syncthreads();
  float tot = wsum[0] + wsum[1] + wsum[2] + wsum[3];
  float rs = rsqrtf(tot * (1.0f / 1024.0f) + 1e-6f);
  const float4 wv = ((const float4*)w)[t];
  u16x4 o4;
  o4[0] = bf16r(v.x * rs * wv.x);
  o4[1] = bf16r(v.y * rs * wv.y);
  o4[2] = bf16r(v.z * rs * wv.z);
  o4[3] = bf16r(v.w * rs * wv.w);
  *(u16x4*)(out + (size_t)row * 1024 + t * 4) = o4;
}

// ---------------- 128x128 bf16 MFMA GEMM, K=1024, M=4096, N=1024 ----------
// mode 0: out -> q (scaled by log2e), k in [bh][s][64]; v transposed+slot-
//         permuted into [bh][d][2048]
// mode 1: out -> fp32 row-major d_out
__global__ __launch_bounds__(256) void k_gemm(const u16* __restrict__ A,
                                              const u16* __restrict__ Bt,
                                              u16* __restrict__ outB,
                                              float* __restrict__ outF, int mode) {
  const int t = threadIdx.x, lane = t & 63, w = t >> 6;
  const int wr = w >> 1, wc = w & 1;
  const int m0 = blockIdx.y << 7, n0 = blockIdx.x << 7;
  const int z = blockIdx.z;
  const u16* Btm = Bt + (size_t)z * (1024 * 1024);
  __shared__ u16 As[8192], Bs[8192];

  f32x4 acc[4][4];
#pragma unroll
  for (int i = 0; i < 4; ++i)
#pragma unroll
    for (int j = 0; j < 4; ++j) acc[i][j] = (f32x4){0.f, 0.f, 0.f, 0.f};

  for (int k0 = 0; k0 < 1024; k0 += 64) {
#pragma unroll
    for (int i = 0; i < 4; ++i) {
      const int o = ((i * 4 + w) * 64 + lane) << 4;  // LDS byte offset (linear)
      const int r = o >> 7;
      const int cb = (o & 127) ^ ((r & 7) << 4);  // pre-swizzled global source
      GLOAD16((const char*)A + (size_t)(m0 + r) * 2048 + (k0 << 1) + cb,
              (char*)As + (i * 4 + w) * 1024);
      GLOAD16((const char*)Btm + (size_t)(n0 + r) * 2048 + (k0 << 1) + cb,
              (char*)Bs + (i * 4 + w) * 1024);
    }
    __syncthreads();
#pragma unroll
    for (int kk = 0; kk < 2; ++kk) {
      bf16x8 af[4], bfr[4];
#pragma unroll
      for (int mi = 0; mi < 4; ++mi) {
        int r = (wr << 6) + (mi << 4) + (lane & 15);
        int cb = ((kk << 6) + ((lane >> 4) << 4)) ^ ((r & 7) << 4);
        af[mi] = ldfrag(As + (((r << 7) + cb) >> 1));
      }
#pragma unroll
      for (int ni = 0; ni < 4; ++ni) {
        int r = (wc << 6) + (ni << 4) + (lane & 15);
        int cb = ((kk << 6) + ((lane >> 4) << 4)) ^ ((r & 7) << 4);
        bfr[ni] = ldfrag(Bs + (((r << 7) + cb) >> 1));
      }
#pragma unroll
      for (int mi = 0; mi < 4; ++mi)
#pragma unroll
        for (int ni = 0; ni < 4; ++ni)
          acc[mi][ni] = mfma16(af[mi], bfr[ni], acc[mi][ni]);
    }
    __syncthreads();
  }

  const int rbase = (lane >> 4) << 2;
  const int cl = lane & 15;
  if (mode == 0) {
    u16* dst = outB + (size_t)z * QKV_MAT_STRIDE;
    const float scl = (z == 0) ? LOG2E : 1.0f;
#pragma unroll
    for (int mi = 0; mi < 4; ++mi)
#pragma unroll
      for (int ni = 0; ni < 4; ++ni)
#pragma unroll
        for (int i = 0; i < 4; ++i) {
          int rg = m0 + (wr << 6) + (mi << 4) + rbase + i;  // b*2048+s
          int cg = n0 + (wc << 6) + (ni << 4) + cl;         // h*64+d
          int b = rg >> 11, s = rg & 2047, h = cg >> 6, d = cg & 63;
          if (z < 2) {
            dst[(((size_t)(b * 16 + h)) * 2048 + s) * 64 + d] =
                bf16r(acc[mi][ni][i] * scl);
          } else {
            // V transposed [bh][d][2048] with k-slot permutation within each
            // 32-block: o<16 -> 2o, o>=16 -> 2(o-16)+1  (pairs (c,c+16) adjacent)
            int o = s & 31;
            int slot = (o < 16) ? (2 * o) : (2 * (o - 16) + 1);
            int sp = (s & ~31) | slot;
            dst[(((size_t)(b * 16 + h)) * 64 + d) * 2048 + sp] =
                bf16r(acc[mi][ni][i]);
          }
        }
  } else {
#pragma unroll
    for (int mi = 0; mi < 4; ++mi)
#pragma unroll
      for (int ni = 0; ni < 4; ++ni)
#pragma unroll
        for (int i = 0; i < 4; ++i) {
          int rg = m0 + (wr << 6) + (mi << 4) + rbase + i;
          int cg = n0 + (wc << 6) + (ni << 4) + cl;
          outF[(size_t)rg * 1024 + cg] = acc[mi][ni][i];
        }
  }
}

// ---------------- flash attention, max-free, direct-global fragments ------
// grid (32 qblocks, 32 bh), 4 waves/block, 16 q-rows/wave, K/V chunks of 64.
__global__ __launch_bounds__(256) void k_attn(
    const u16* __restrict__ qkv, const int* __restrict__ positions,
    const float* __restrict__ kbias, const signed char* __restrict__ lut8,
    const float* __restrict__ rel_emb, u16* __restrict__ ctx) {
  const int t = threadIdx.x, lane = t & 63, w = t >> 6;
  const int g = lane >> 4, c = lane & 15;
  const int qb = blockIdx.x, bh = blockIdx.y;
  const int b = bh >> 4, h = bh & 15;
  const size_t hb = (size_t)bh * (2048 * 64);
  const u16* Qg = qkv + hb + (size_t)qb * 64 * 64;
  const u16* Kg = qkv + (size_t)QKV_MAT_STRIDE + hb;
  const u16* Vt = qkv + (size_t)2 * QKV_MAT_STRIDE + hb;  // [64][2048] slot-perm

  __shared__ float relbs[32];
  __shared__ u16 lutb[8208];       // bf16(relb*log2e) by rel+4096
  __shared__ float kbs[2048];      // per-key bias * log2e
  __shared__ u16 poss[2048];       // positions (fit u16)
  __shared__ alignas(16) u16 Ps[4][1024];  // per-wave P tile, swizzled

  if (t < 32) relbs[t] = rel_emb[t * 16 + h] * LOG2E;
  __syncthreads();
  for (int i = t; i < 8193; i += 256) lutb[i] = bf16r(relbs[(int)lut8[i]]);
  for (int i = t; i < 2048; i += 256) {
    kbs[i] = kbias[b * 2048 + i];
    poss[i] = (u16)positions[b * 2048 + i];
  }

  // Q fragments (A-operand rows m = c)
  bf16x8 qa[2];
  {
    const u16* qrow = Qg + (size_t)(w * 16 + c) * 64;
    qa[0] = ldfrag(qrow + g * 8);
    qa[1] = ldfrag(qrow + 32 + g * 8);
  }
  const int qrow0 = qb * 64 + w * 16 + g * 4;
  int npq[4];
#pragma unroll
  for (int i = 0; i < 4; ++i)
    npq[i] = 4096 - positions[b * 2048 + qrow0 + i];
  __syncthreads();

  f32x4 oacc[4];
#pragma unroll
  for (int i = 0; i < 4; ++i) oacc[i] = (f32x4){0.f, 0.f, 0.f, 0.f};
  float lpart[4] = {0.f, 0.f, 0.f, 0.f};

  for (int kc = 0; kc < 2048; kc += 64) {
    // S = Q K^T : rows q = g*4+i, col kv = sub*16+c
    f32x4 sc[4];
#pragma unroll
    for (int sub = 0; sub < 4; ++sub) {
      const u16* krow = Kg + (size_t)(kc + sub * 16 + c) * 64;
      f32x4 a = (f32x4){0.f, 0.f, 0.f, 0.f};
      a = mfma16(qa[0], ldfrag(krow + g * 8), a);
      a = mfma16(qa[1], ldfrag(krow + 32 + g * 8), a);
      sc[sub] = a;
    }
    // bias + exp2 (log2 domain, no running max) + l accumulation
#pragma unroll
    for (int sub = 0; sub < 4; ++sub) {
      int ki = kc + sub * 16 + c;
      float kb = kbs[ki];
      int pk = (int)poss[ki];
#pragma unroll
      for (int i = 0; i < 4; ++i) {
        float rb = bf2f(lutb[pk + npq[i]]);
        float p = fast_exp2(sc[sub][i] + kb + rb);
        sc[sub][i] = p;
        lpart[i] += p;
      }
    }
    // pack P pairs (col c, col c+16) -> adjacent slots (2c,2c+1), swizzled
#pragma unroll
    for (int kk = 0; kk < 2; ++kk)
#pragma unroll
      for (int i = 0; i < 4; ++i) {
        int r = g * 4 + i;
        u32 pr;
        asm("v_cvt_pk_bf16_f32 %0, %1, %2"
            : "=v"(pr)
            : "v"(sc[2 * kk][i]), "v"(sc[2 * kk + 1][i]));
        int bo = ((r << 7) + (kk << 6) + (c << 2)) ^ ((r & 7) << 4);
        *(u32*)((char*)&Ps[w][0] + bo) = pr;
      }
    // O += P V : pa rows m = c (q-row w*16+c), V from global (slot-permuted)
#pragma unroll
    for (int kk = 0; kk < 2; ++kk) {
      int bo = ((c << 7) + (kk << 6) + (g << 4)) ^ ((c & 7) << 4);
      bf16x8 pa = __builtin_bit_cast(bf16x8, *(u16x8*)((char*)&Ps[w][0] + bo));
#pragma unroll
      for (int d2 = 0; d2 < 4; ++d2) {
        const u16* vrow = Vt + (size_t)(d2 * 16 + c) * 2048 + kc;
        oacc[d2] = mfma16(pa, ldfrag(vrow + kk * 32 + g * 8), oacc[d2]);
      }
    }
  }

  // final l reduce across the 16 col-lanes, then normalize + write
  float inv[4];
#pragma unroll
  for (int i = 0; i < 4; ++i) {
    float l = lpart[i];
#pragma unroll
    for (int o = 1; o < 16; o <<= 1) l += __shfl_xor(l, o);
    inv[i] = 1.0f / l;
  }
#pragma unroll
  for (int d2 = 0; d2 < 4; ++d2)
#pragma unroll
    for (int i = 0; i < 4; ++i)
      ctx[((size_t)b * 2048 + qrow0 + i) * 1024 + h * 64 + d2 * 16 + c] =
          bf16r(oacc[d2][i] * inv[i]);
}

// ---------------- launch ----------------
extern "C" void kernel_launch(void* const* d_in, const int* in_sizes, int n_in,
                              void* d_out, int out_size, void* d_ws, size_t ws_size,
                              hipStream_t stream) {
  const float* hs = (const float*)d_in[0];
  const int* pos = (const int*)d_in[1];
  const float* mask = (const float*)d_in[2];
  const float* ss = (const float*)d_in[3];
  const int* nd = (const int*)d_in[4];
  const float* lnw = (const float*)d_in[5];
  const float* Wq = (const float*)d_in[6];
  const float* Wk = (const float*)d_in[7];
  const float* Wv = (const float*)d_in[8];
  const float* Wo = (const float*)d_in[9];
  const float* rel = (const float*)d_in[10];

  char* ws = (char*)d_ws;
  signed char* lut8 = (signed char*)ws;            //      0 .. 8448
  float* kb = (float*)(ws + 8448);                 //   8448 .. 24832
  u16* normed = (u16*)(ws + 24832);                //  +8 MB
  u16* wtqkv = (u16*)(ws + 8413440);               //  +6 MB
  u16* wto = (u16*)(ws + 14704896);                //  +2 MB
  u16* qkv = (u16*)(ws + 16802048);                //  +24 MB
  u16* ctx = (u16*)(ws + 41967872);                //  +8 MB  (end 50356480)
  if (ws_size < 50356480) return;  // loud failure instead of corruption

  k_build_lut<<<33, 256, 0, stream>>>(lut8);
  k_kbias<<<16, 256, 0, stream>>>(mask, ss, nd, kb);
  k_transpose<<<dim3(32, 32, 4), dim3(32, 8), 0, stream>>>(Wq, Wk, Wv, Wo, wtqkv, wto);
  k_rmsnorm<<<4096, 256, 0, stream>>>(hs, lnw, normed);
  k_gemm<<<dim3(8, 32, 3), 256, 0, stream>>>(normed, wtqkv, qkv, nullptr, 0);
  k_attn<<<dim3(32, 32), 256, 0, stream>>>(qkv, pos, kb, lut8, rel, ctx);
  k_gemm<<<dim3(8, 32, 1), 256, 0, stream>>>(ctx, wto, nullptr, (float*)d_out, 1);
}

// Round 3
// 185.132 us; speedup vs baseline: 1.8032x; 1.8032x over previous
//
#include <hip/hip_runtime.h>
#include <math.h>

typedef unsigned short u16;
typedef unsigned int u32;
typedef __attribute__((ext_vector_type(8))) __bf16 bf16x8;
typedef __attribute__((ext_vector_type(8))) u16 u16x8;
typedef __attribute__((ext_vector_type(4))) u16 u16x4;
typedef __attribute__((ext_vector_type(4))) float f32x4;

#define GLOAD16(gp, lp)                                                        \
  __builtin_amdgcn_global_load_lds(                                            \
      (const __attribute__((address_space(1))) unsigned int*)(gp),             \
      (__attribute__((address_space(3))) unsigned int*)(lp), 16, 0, 0)

#define LOG2E 1.4426950408889634f

__device__ __forceinline__ u16 bf16r(float f) {
  unsigned u = __float_as_uint(f);
  u += 0x7fff + ((u >> 16) & 1);
  return (u16)(u >> 16);
}

__device__ __forceinline__ bf16x8 ldfrag(const u16* p) {
  return __builtin_bit_cast(bf16x8, *(const u16x8*)p);
}

__device__ __forceinline__ f32x4 mfma16(bf16x8 a, bf16x8 b, f32x4 c) {
  return __builtin_amdgcn_mfma_f32_16x16x32_bf16(a, b, c, 0, 0, 0);
}

__device__ __forceinline__ float fast_exp2(float x) {
  float r;
  asm("v_exp_f32 %0, %1" : "=v"(r) : "v"(x));
  return r;
}

// ---------------- constants ----------------
// B=2 S=2048 D_MODEL=1024 H=16 DKV=64, inner=1024
#define QKV_MAT_STRIDE (2 * 16 * 2048 * 64)  // elements per one of q/k/v

// ---------------- LUT: T5 relative bucket of rel in [-4096,4096] -----------
__global__ void k_build_lut(signed char* __restrict__ lut8) {
  int i = blockIdx.x * 256 + threadIdx.x;
  if (i > 8192) return;
  int rel = i - 4096;
  int ret = rel > 0 ? 16 : 0;
  int n = rel < 0 ? -rel : rel;
  int bucket;
  if (n < 8) {
    bucket = n;
  } else {
    int vl = 8 + (int)(log((double)n / 8.0) / log(16.0) * 8.0);
    bucket = vl > 15 ? 15 : vl;
  }
  lut8[i] = (signed char)(ret + bucket);
}

// ---------------- per-key bias (pre-scaled by log2e) ----------------------
__global__ void k_kbias(const float* __restrict__ mask, const float* __restrict__ ss,
                        const int* __restrict__ nd, float* __restrict__ kb) {
  int i = blockIdx.x * 256 + threadIdx.x;  // < 4096
  kb[i] = (-1000.0f * (1.0f - mask[i]) + logf(ss[i] + 1e-4f) +
           logf((float)nd[i] + 1e-4f)) * LOG2E;
}

// ---------------- weight transpose fp32 [k][n] -> bf16 [n][k] --------------
__global__ __launch_bounds__(256) void k_transpose(
    const float* __restrict__ Wq, const float* __restrict__ Wk,
    const float* __restrict__ Wv, const float* __restrict__ Wo,
    u16* __restrict__ wtqkv, u16* __restrict__ wto) {
  int z = blockIdx.z;
  const float* W = (z == 0) ? Wq : (z == 1) ? Wk : (z == 2) ? Wv : Wo;
  u16* Wt = (z < 3) ? (wtqkv + (size_t)z * 1024 * 1024) : wto;
  __shared__ float tile[32][33];
  int n0 = blockIdx.x * 32, k0 = blockIdx.y * 32;
  int tx = threadIdx.x, ty = threadIdx.y;  // (32,8)
#pragma unroll
  for (int j = 0; j < 4; ++j)
    tile[ty + 8 * j][tx] = W[(size_t)(k0 + ty + 8 * j) * 1024 + n0 + tx];
  __syncthreads();
#pragma unroll
  for (int j = 0; j < 4; ++j)
    Wt[(size_t)(n0 + ty + 8 * j) * 1024 + k0 + tx] = bf16r(tile[tx][ty + 8 * j]);
}

// ---------------- RMSNorm (T5 LayerNorm) -> bf16 --------------------------
__global__ __launch_bounds__(256) void k_rmsnorm(const float* __restrict__ x,
                                                 const float* __restrict__ w,
                                                 u16* __restrict__ out) {
  int row = blockIdx.x;  // 0..4095
  int t = threadIdx.x;
  const float4 v = ((const float4*)(x + (size_t)row * 1024))[t];
  float ss = v.x * v.x + v.y * v.y + v.z * v.z + v.w * v.w;
#pragma unroll
  for (int o = 1; o < 64; o <<= 1) ss += __shfl_xor(ss, o);
  __shared__ float wsum[4];
  if ((t & 63) == 0) wsum[t >> 6] = ss;
  __syncthreads();
  float tot = wsum[0] + wsum[1] + wsum[2] + wsum[3];
  float rs = rsqrtf(tot * (1.0f / 1024.0f) + 1e-6f);
  const float4 wv = ((const float4*)w)[t];
  u16x4 o4;
  o4[0] = bf16r(v.x * rs * wv.x);
  o4[1] = bf16r(v.y * rs * wv.y);
  o4[2] = bf16r(v.z * rs * wv.z);
  o4[3] = bf16r(v.w * rs * wv.w);
  *(u16x4*)(out + (size_t)row * 1024 + t * 4) = o4;
}

// ---------------- 128x128 bf16 MFMA GEMM, K=1024, M=4096, N=1024 ----------
// mode 0: z=0 -> q*log2e, z=1 -> k, both [bh][s][64]; z=2 -> v transposed +
//         slot-permuted to [bh][d][2048] (coalesced via LDS tile)
// mode 1: out -> fp32 row-major d_out
__global__ __launch_bounds__(256) void k_gemm(const u16* __restrict__ A,
                                              const u16* __restrict__ Bt,
                                              u16* __restrict__ outB,
                                              float* __restrict__ outF, int mode) {
  const int t = threadIdx.x, lane = t & 63, w = t >> 6;
  const int wr = w >> 1, wc = w & 1;
  const int m0 = blockIdx.y << 7, n0 = blockIdx.x << 7;
  const int z = blockIdx.z;
  const u16* Btm = Bt + (size_t)z * (1024 * 1024);
  __shared__ u16 smem[16384];  // As | Bs ; reused as transpose tile for z==2
  u16* As = smem;
  u16* Bs = smem + 8192;

  f32x4 acc[4][4];
#pragma unroll
  for (int i = 0; i < 4; ++i)
#pragma unroll
    for (int j = 0; j < 4; ++j) acc[i][j] = (f32x4){0.f, 0.f, 0.f, 0.f};

  for (int k0 = 0; k0 < 1024; k0 += 64) {
#pragma unroll
    for (int i = 0; i < 4; ++i) {
      const int o = ((i * 4 + w) * 64 + lane) << 4;  // LDS byte offset (linear)
      const int r = o >> 7;
      const int cb = (o & 127) ^ ((r & 7) << 4);  // pre-swizzled global source
      GLOAD16((const char*)A + (size_t)(m0 + r) * 2048 + (k0 << 1) + cb,
              (char*)As + (i * 4 + w) * 1024);
      GLOAD16((const char*)Btm + (size_t)(n0 + r) * 2048 + (k0 << 1) + cb,
              (char*)Bs + (i * 4 + w) * 1024);
    }
    __syncthreads();
#pragma unroll
    for (int kk = 0; kk < 2; ++kk) {
      bf16x8 af[4], bfr[4];
#pragma unroll
      for (int mi = 0; mi < 4; ++mi) {
        int r = (wr << 6) + (mi << 4) + (lane & 15);
        int cb = ((kk << 6) + ((lane >> 4) << 4)) ^ ((r & 7) << 4);
        af[mi] = ldfrag(As + (((r << 7) + cb) >> 1));
      }
#pragma unroll
      for (int ni = 0; ni < 4; ++ni) {
        int r = (wc << 6) + (ni << 4) + (lane & 15);
        int cb = ((kk << 6) + ((lane >> 4) << 4)) ^ ((r & 7) << 4);
        bfr[ni] = ldfrag(Bs + (((r << 7) + cb) >> 1));
      }
#pragma unroll
      for (int mi = 0; mi < 4; ++mi)
#pragma unroll
        for (int ni = 0; ni < 4; ++ni)
          acc[mi][ni] = mfma16(af[mi], bfr[ni], acc[mi][ni]);
    }
    __syncthreads();
  }

  const int rbase = (lane >> 4) << 2;
  const int cl = lane & 15;
  if (mode == 0) {
    u16* dst = outB + (size_t)z * QKV_MAT_STRIDE;
    if (z < 2) {
      const float scl = (z == 0) ? LOG2E : 1.0f;
#pragma unroll
      for (int mi = 0; mi < 4; ++mi)
#pragma unroll
        for (int ni = 0; ni < 4; ++ni)
#pragma unroll
          for (int i = 0; i < 4; ++i) {
            int rg = m0 + (wr << 6) + (mi << 4) + rbase + i;  // b*2048+s
            int cg = n0 + (wc << 6) + (ni << 4) + cl;         // h*64+d
            int b = rg >> 11, s = rg & 2047, h = cg >> 6, d = cg & 63;
            dst[(((size_t)(b * 16 + h)) * 2048 + s) * 64 + d] =
                bf16r(acc[mi][ni][i] * scl);
          }
    } else {
      // V: transpose via LDS, slot-permute s within 32-blocks, coalesced out.
      const int s0 = m0 & 2047, bb = m0 >> 11;
#pragma unroll
      for (int h2 = 0; h2 < 2; ++h2) {
        if (h2) __syncthreads();
#pragma unroll
        for (int nb = 0; nb < 2; ++nb) {
          int ni = 2 * h2 + nb;
          int ld = wc * 32 + nb * 16 + cl;
#pragma unroll
          for (int mi = 0; mi < 4; ++mi)
#pragma unroll
            for (int i = 0; i < 4; ++i) {
              int sl = (wr << 6) + (mi << 4) + rbase + i;
              int o = sl & 31;
              int sp = (sl & ~31) | ((o < 16) ? (o << 1) : (((o - 16) << 1) | 1));
              smem[ld * 136 + sp] = bf16r(acc[mi][ni][i]);
            }
        }
        __syncthreads();
#pragma unroll
        for (int rr = 0; rr < 4; ++rr) {
          int ld = rr * 16 + (t >> 4);
          int cu = (t & 15) * 8;
          int cgo = ((ld >> 5) << 6) + ((2 * h2 + ((ld >> 4) & 1)) << 4) + (ld & 15);
          int cg = n0 + cgo;
          int hh = cg >> 6, d = cg & 63;
          u16x8 val = *(u16x8*)&smem[ld * 136 + cu];
          *(u16x8*)&dst[(((size_t)(bb * 16 + hh)) * 64 + d) * 2048 + s0 + cu] = val;
        }
      }
    }
  } else {
#pragma unroll
    for (int mi = 0; mi < 4; ++mi)
#pragma unroll
      for (int ni = 0; ni < 4; ++ni)
#pragma unroll
        for (int i = 0; i < 4; ++i) {
          int rg = m0 + (wr << 6) + (mi << 4) + rbase + i;
          int cg = n0 + (wc << 6) + (ni << 4) + cl;
          outF[(size_t)rg * 1024 + cg] = acc[mi][ni][i];
        }
  }
}

// ---------------- flash attention: LDS-dbuf staging + max-free softmax ----
// grid (32 qblocks, 32 bh), 4 waves, 16 q-rows/wave, K/V chunks of 64.
__device__ __forceinline__ void attn_chunk(
    const u16* __restrict__ ksb, const u16* __restrict__ vsb, u16* __restrict__ psw,
    int kc, const bf16x8* qa, const float* kbs, const u16* poss,
    const float* lutf, const int* pq, int g, int c, f32x4* oacc, float* lpart) {
  f32x4 sc[4];
#pragma unroll
  for (int sub = 0; sub < 4; ++sub) {
    int r = sub * 16 + c;
    f32x4 a = (f32x4){0.f, 0.f, 0.f, 0.f};
#pragma unroll
    for (int kk = 0; kk < 2; ++kk) {
      int cb = ((kk << 6) + (g << 4)) ^ ((r & 7) << 4);
      a = mfma16(qa[kk], ldfrag(ksb + (((r << 7) + cb) >> 1)), a);
    }
    sc[sub] = a;
  }
#pragma unroll
  for (int sub = 0; sub < 4; ++sub) {
    int ki = kc + sub * 16 + c;
    float kb = kbs[ki];
    int pk = (int)poss[ki];
#pragma unroll
    for (int i = 0; i < 4; ++i) {
      int rel = pk - pq[i];
      rel = rel < -92 ? -92 : (rel > 92 ? 92 : rel);
      float p = fast_exp2(sc[sub][i] + kb + lutf[rel + 92]);
      sc[sub][i] = p;
      lpart[i] += p;
    }
  }
  // pack P pairs (col c, col c+16) -> adjacent slots (2c,2c+1), swizzled
#pragma unroll
  for (int kk = 0; kk < 2; ++kk)
#pragma unroll
    for (int i = 0; i < 4; ++i) {
      int r = g * 4 + i;
      u32 pr;
      asm("v_cvt_pk_bf16_f32 %0, %1, %2"
          : "=v"(pr)
          : "v"(sc[2 * kk][i]), "v"(sc[2 * kk + 1][i]));
      int bo = ((r << 7) + (kk << 6) + (c << 2)) ^ ((r & 7) << 4);
      *(u32*)((char*)psw + bo) = pr;
    }
  // O += P V  (V staged slot-permuted)
#pragma unroll
  for (int kk = 0; kk < 2; ++kk) {
    int bo = ((c << 7) + (kk << 6) + (g << 4)) ^ ((c & 7) << 4);
    bf16x8 pa = __builtin_bit_cast(bf16x8, *(u16x8*)((char*)psw + bo));
#pragma unroll
    for (int d2 = 0; d2 < 4; ++d2) {
      int vr = d2 * 16 + c;
      int vcb = ((kk << 6) + (g << 4)) ^ ((vr & 7) << 4);
      oacc[d2] = mfma16(pa, ldfrag(vsb + (((vr << 7) + vcb) >> 1)), oacc[d2]);
    }
  }
}

__global__ __launch_bounds__(256) void k_attn(
    const u16* __restrict__ qkv, const int* __restrict__ positions,
    const float* __restrict__ kbias, const signed char* __restrict__ lut8,
    const float* __restrict__ rel_emb, u16* __restrict__ ctx) {
  const int t = threadIdx.x, lane = t & 63, w = t >> 6;
  const int g = lane >> 4, c = lane & 15;
  const int qb = blockIdx.x, bh = blockIdx.y;
  const int b = bh >> 4, h = bh & 15;
  const size_t hb = (size_t)bh * (2048 * 64);
  const u16* Qg = qkv + hb + (size_t)qb * 64 * 64;
  const char* Kg = (const char*)(qkv + (size_t)QKV_MAT_STRIDE + hb);
  const char* Vg = (const char*)(qkv + (size_t)2 * QKV_MAT_STRIDE + hb);

  __shared__ u16 Ks[2][4096], Vs[2][4096];   // double-buffered chunks (8KB ea)
  __shared__ alignas(16) u16 Ps[4][1024];
  __shared__ float kbs[2048];
  __shared__ u16 poss[2048];
  __shared__ float lutf[192];  // bucket bias * log2e for rel in [-92,92]

  for (int i = t; i < 185; i += 256)
    lutf[i] = rel_emb[(int)lut8[i - 92 + 4096] * 16 + h] * LOG2E;
  for (int i = t; i < 2048; i += 256) {
    kbs[i] = kbias[b * 2048 + i];
    poss[i] = (u16)positions[b * 2048 + i];
  }

  bf16x8 qa[2];
  {
    const u16* qrow = Qg + (size_t)(w * 16 + c) * 64;
    qa[0] = ldfrag(qrow + g * 8);
    qa[1] = ldfrag(qrow + 32 + g * 8);
  }
  const int qrow0 = qb * 64 + w * 16 + g * 4;
  int pq[4];
#pragma unroll
  for (int i = 0; i < 4; ++i) pq[i] = positions[b * 2048 + qrow0 + i];

  // per-lane staging source pointers (pre-swizzled for linear LDS dest)
  const char* srcK[2];
  const char* srcV[2];
#pragma unroll
  for (int i = 0; i < 2; ++i) {
    int o = ((i * 4 + w) * 64 + lane) << 4;
    int r = o >> 7;
    int cb = (o & 127) ^ ((r & 7) << 4);
    srcK[i] = Kg + r * 128 + cb;       // advance 8192 B/chunk (64 rows)
    srcV[i] = Vg + r * 4096 + cb;      // advance 128 B/chunk (64 cols)
  }

#define STAGE(bi)                                                   \
  do {                                                              \
    GLOAD16(srcK[0], (char*)Ks[bi] + w * 1024);                     \
    GLOAD16(srcK[1], (char*)Ks[bi] + 4096 + w * 1024);              \
    GLOAD16(srcV[0], (char*)Vs[bi] + w * 1024);                     \
    GLOAD16(srcV[1], (char*)Vs[bi] + 4096 + w * 1024);              \
    srcK[0] += 8192; srcK[1] += 8192;                               \
    srcV[0] += 128;  srcV[1] += 128;                                \
  } while (0)

  f32x4 oacc[4];
#pragma unroll
  for (int i = 0; i < 4; ++i) oacc[i] = (f32x4){0.f, 0.f, 0.f, 0.f};
  float lpart[4] = {0.f, 0.f, 0.f, 0.f};

  STAGE(0);
  __syncthreads();

  int kc = 0;
  for (int t2 = 0; t2 < 16; ++t2) {
    STAGE(1);  // prefetch chunk kc+64 while computing kc
    attn_chunk(Ks[0], Vs[0], &Ps[w][0], kc, qa, kbs, poss, lutf, pq, g, c,
               oacc, lpart);
    __syncthreads();
    kc += 64;
    if (t2 < 15) STAGE(0);
    attn_chunk(Ks[1], Vs[1], &Ps[w][0], kc, qa, kbs, poss, lutf, pq, g, c,
               oacc, lpart);
    __syncthreads();
    kc += 64;
  }
#undef STAGE

  float inv[4];
#pragma unroll
  for (int i = 0; i < 4; ++i) {
    float l = lpart[i];
#pragma unroll
    for (int o = 1; o < 16; o <<= 1) l += __shfl_xor(l, o);
    inv[i] = 1.0f / l;
  }
#pragma unroll
  for (int d2 = 0; d2 < 4; ++d2)
#pragma unroll
    for (int i = 0; i < 4; ++i)
      ctx[((size_t)b * 2048 + qrow0 + i) * 1024 + h * 64 + d2 * 16 + c] =
          bf16r(oacc[d2][i] * inv[i]);
}

// ---------------- launch ----------------
extern "C" void kernel_launch(void* const* d_in, const int* in_sizes, int n_in,
                              void* d_out, int out_size, void* d_ws, size_t ws_size,
                              hipStream_t stream) {
  const float* hs = (const float*)d_in[0];
  const int* pos = (const int*)d_in[1];
  const float* mask = (const float*)d_in[2];
  const float* ss = (const float*)d_in[3];
  const int* nd = (const int*)d_in[4];
  const float* lnw = (const float*)d_in[5];
  const float* Wq = (const float*)d_in[6];
  const float* Wk = (const float*)d_in[7];
  const float* Wv = (const float*)d_in[8];
  const float* Wo = (const float*)d_in[9];
  const float* rel = (const float*)d_in[10];

  char* ws = (char*)d_ws;
  signed char* lut8 = (signed char*)ws;            //      0 .. 8448
  float* kb = (float*)(ws + 8448);                 //   8448 .. 24832
  u16* normed = (u16*)(ws + 24832);                //  +8 MB
  u16* wtqkv = (u16*)(ws + 8413440);               //  +6 MB
  u16* wto = (u16*)(ws + 14704896);                //  +2 MB
  u16* qkv = (u16*)(ws + 16802048);                //  +24 MB
  u16* ctx = (u16*)(ws + 41967872);                //  +8 MB  (end 50356480)
  if (ws_size < 50356480) return;  // loud failure instead of corruption

  k_build_lut<<<33, 256, 0, stream>>>(lut8);
  k_kbias<<<16, 256, 0, stream>>>(mask, ss, nd, kb);
  k_transpose<<<dim3(32, 32, 4), dim3(32, 8), 0, stream>>>(Wq, Wk, Wv, Wo, wtqkv, wto);
  k_rmsnorm<<<4096, 256, 0, stream>>>(hs, lnw, normed);
  k_gemm<<<dim3(8, 32, 3), 256, 0, stream>>>(normed, wtqkv, qkv, nullptr, 0);
  k_attn<<<dim3(32, 32), 256, 0, stream>>>(qkv, pos, kb, lut8, rel, ctx);
  k_gemm<<<dim3(8, 32, 1), 256, 0, stream>>>(ctx, wto, nullptr, (float*)d_out, 1);
}

// Round 4
// 142.200 us; speedup vs baseline: 2.3477x; 1.3019x over previous
//
#include <hip/hip_runtime.h>
#include <math.h>

typedef unsigned short u16;
typedef unsigned int u32;
typedef __attribute__((ext_vector_type(8))) __bf16 bf16x8;
typedef __attribute__((ext_vector_type(8))) u16 u16x8;
typedef __attribute__((ext_vector_type(4))) u16 u16x4;
typedef __attribute__((ext_vector_type(4))) float f32x4;

#define GLOAD16(gp, lp)                                                        \
  __builtin_amdgcn_global_load_lds(                                            \
      (const __attribute__((address_space(1))) unsigned int*)(gp),             \
      (__attribute__((address_space(3))) unsigned int*)(lp), 16, 0, 0)

#define LOG2E 1.4426950408889634f

__device__ __forceinline__ u16 bf16r(float f) {
  unsigned u = __float_as_uint(f);
  u += 0x7fff + ((u >> 16) & 1);
  return (u16)(u >> 16);
}

__device__ __forceinline__ bf16x8 ldfrag(const u16* p) {
  return __builtin_bit_cast(bf16x8, *(const u16x8*)p);
}

__device__ __forceinline__ f32x4 mfma16(bf16x8 a, bf16x8 b, f32x4 c) {
  return __builtin_amdgcn_mfma_f32_16x16x32_bf16(a, b, c, 0, 0, 0);
}

__device__ __forceinline__ float fast_exp2(float x) {
  float r;
  asm("v_exp_f32 %0, %1" : "=v"(r) : "v"(x));
  return r;
}

// ---------------- constants ----------------
// B=2 S=2048 D_MODEL=1024 H=16 DKV=64, inner=1024
#define QKV_MAT_STRIDE (2 * 16 * 2048 * 64)  // elements per one of q/k/v

// ---------------- LUT: T5 relative bucket of rel in [-4096,4096] -----------
__global__ void k_build_lut(signed char* __restrict__ lut8) {
  int i = blockIdx.x * 256 + threadIdx.x;
  if (i > 8192) return;
  int rel = i - 4096;
  int ret = rel > 0 ? 16 : 0;
  int n = rel < 0 ? -rel : rel;
  int bucket;
  if (n < 8) {
    bucket = n;
  } else {
    int vl = 8 + (int)(log((double)n / 8.0) / log(16.0) * 8.0);
    bucket = vl > 15 ? 15 : vl;
  }
  lut8[i] = (signed char)(ret + bucket);
}

// ---------------- per-key weight wk = e^{-1000(1-m)}(ss+1e-4)(nd+1e-4) -----
// wkf: f32 linear; wkp: bf16 slot-permuted within 32-blocks (for l-MFMA frag)
__global__ void k_wk(const float* __restrict__ mask, const float* __restrict__ ss,
                     const int* __restrict__ nd, float* __restrict__ wkf,
                     u16* __restrict__ wkp) {
  int i = blockIdx.x * 256 + threadIdx.x;  // < 4096
  float wv = __expf(-1000.0f * (1.0f - mask[i])) * (ss[i] + 1e-4f) *
             ((float)nd[i] + 1e-4f);
  wkf[i] = wv;
  int o = i & 31;
  int slot = (o < 16) ? (o << 1) : (((o - 16) << 1) | 1);
  wkp[(i & ~31) | slot] = bf16r(wv);
}

// ---------------- weight transpose fp32 [k][n] -> bf16 [n][k] --------------
__global__ __launch_bounds__(256) void k_transpose(
    const float* __restrict__ Wq, const float* __restrict__ Wk,
    const float* __restrict__ Wv, const float* __restrict__ Wo,
    u16* __restrict__ wtqkv, u16* __restrict__ wto) {
  int z = blockIdx.z;
  const float* W = (z == 0) ? Wq : (z == 1) ? Wk : (z == 2) ? Wv : Wo;
  u16* Wt = (z < 3) ? (wtqkv + (size_t)z * 1024 * 1024) : wto;
  __shared__ float tile[32][33];
  int n0 = blockIdx.x * 32, k0 = blockIdx.y * 32;
  int tx = threadIdx.x, ty = threadIdx.y;  // (32,8)
#pragma unroll
  for (int j = 0; j < 4; ++j)
    tile[ty + 8 * j][tx] = W[(size_t)(k0 + ty + 8 * j) * 1024 + n0 + tx];
  __syncthreads();
#pragma unroll
  for (int j = 0; j < 4; ++j)
    Wt[(size_t)(n0 + ty + 8 * j) * 1024 + k0 + tx] = bf16r(tile[tx][ty + 8 * j]);
}

// ---------------- RMSNorm (T5 LayerNorm) -> bf16 --------------------------
__global__ __launch_bounds__(256) void k_rmsnorm(const float* __restrict__ x,
                                                 const float* __restrict__ w,
                                                 u16* __restrict__ out) {
  int row = blockIdx.x;  // 0..4095
  int t = threadIdx.x;
  const float4 v = ((const float4*)(x + (size_t)row * 1024))[t];
  float ss = v.x * v.x + v.y * v.y + v.z * v.z + v.w * v.w;
#pragma unroll
  for (int o = 1; o < 64; o <<= 1) ss += __shfl_xor(ss, o);
  __shared__ float wsum[4];
  if ((t & 63) == 0) wsum[t >> 6] = ss;
  __syncthreads();
  float tot = wsum[0] + wsum[1] + wsum[2] + wsum[3];
  float rs = rsqrtf(tot * (1.0f / 1024.0f) + 1e-6f);
  const float4 wv = ((const float4*)w)[t];
  u16x4 o4;
  o4[0] = bf16r(v.x * rs * wv.x);
  o4[1] = bf16r(v.y * rs * wv.y);
  o4[2] = bf16r(v.z * rs * wv.z);
  o4[3] = bf16r(v.w * rs * wv.w);
  *(u16x4*)(out + (size_t)row * 1024 + t * 4) = o4;
}

// ---------------- 128x128 bf16 MFMA GEMM, K=1024, M=4096, N=1024 ----------
// mode 0: z=0 -> q*log2e, z=1 -> k, both [bh][s][64]; z=2 -> v*wk transposed
//         + slot-permuted to [bh][d][2048] (coalesced via LDS tile)
// mode 1: out -> fp32 row-major d_out
__global__ __launch_bounds__(256) void k_gemm(const u16* __restrict__ A,
                                              const u16* __restrict__ Bt,
                                              u16* __restrict__ outB,
                                              float* __restrict__ outF,
                                              const float* __restrict__ wkf,
                                              int mode) {
  const int t = threadIdx.x, lane = t & 63, w = t >> 6;
  const int wr = w >> 1, wc = w & 1;
  const int m0 = blockIdx.y << 7, n0 = blockIdx.x << 7;
  const int z = blockIdx.z;
  const u16* Btm = Bt + (size_t)z * (1024 * 1024);
  __shared__ u16 smem[16384];  // As | Bs ; reused as transpose tile for z==2
  u16* As = smem;
  u16* Bs = smem + 8192;

  f32x4 acc[4][4];
#pragma unroll
  for (int i = 0; i < 4; ++i)
#pragma unroll
    for (int j = 0; j < 4; ++j) acc[i][j] = (f32x4){0.f, 0.f, 0.f, 0.f};

  for (int k0 = 0; k0 < 1024; k0 += 64) {
#pragma unroll
    for (int i = 0; i < 4; ++i) {
      const int o = ((i * 4 + w) * 64 + lane) << 4;  // LDS byte offset (linear)
      const int r = o >> 7;
      const int cb = (o & 127) ^ ((r & 7) << 4);  // pre-swizzled global source
      GLOAD16((const char*)A + (size_t)(m0 + r) * 2048 + (k0 << 1) + cb,
              (char*)As + (i * 4 + w) * 1024);
      GLOAD16((const char*)Btm + (size_t)(n0 + r) * 2048 + (k0 << 1) + cb,
              (char*)Bs + (i * 4 + w) * 1024);
    }
    __syncthreads();
#pragma unroll
    for (int kk = 0; kk < 2; ++kk) {
      bf16x8 af[4], bfr[4];
#pragma unroll
      for (int mi = 0; mi < 4; ++mi) {
        int r = (wr << 6) + (mi << 4) + (lane & 15);
        int cb = ((kk << 6) + ((lane >> 4) << 4)) ^ ((r & 7) << 4);
        af[mi] = ldfrag(As + (((r << 7) + cb) >> 1));
      }
#pragma unroll
      for (int ni = 0; ni < 4; ++ni) {
        int r = (wc << 6) + (ni << 4) + (lane & 15);
        int cb = ((kk << 6) + ((lane >> 4) << 4)) ^ ((r & 7) << 4);
        bfr[ni] = ldfrag(Bs + (((r << 7) + cb) >> 1));
      }
#pragma unroll
      for (int mi = 0; mi < 4; ++mi)
#pragma unroll
        for (int ni = 0; ni < 4; ++ni)
          acc[mi][ni] = mfma16(af[mi], bfr[ni], acc[mi][ni]);
    }
    __syncthreads();
  }

  const int rbase = (lane >> 4) << 2;
  const int cl = lane & 15;
  if (mode == 0) {
    u16* dst = outB + (size_t)z * QKV_MAT_STRIDE;
    if (z < 2) {
      const float scl = (z == 0) ? LOG2E : 1.0f;
#pragma unroll
      for (int mi = 0; mi < 4; ++mi)
#pragma unroll
        for (int ni = 0; ni < 4; ++ni)
#pragma unroll
          for (int i = 0; i < 4; ++i) {
            int rg = m0 + (wr << 6) + (mi << 4) + rbase + i;  // b*2048+s
            int cg = n0 + (wc << 6) + (ni << 4) + cl;         // h*64+d
            int b = rg >> 11, s = rg & 2047, h = cg >> 6, d = cg & 63;
            dst[(((size_t)(b * 16 + h)) * 2048 + s) * 64 + d] =
                bf16r(acc[mi][ni][i] * scl);
          }
    } else {
      // V: scale by wk, transpose via LDS, slot-permute s, coalesced out.
      const int s0 = m0 & 2047, bb = m0 >> 11;
#pragma unroll
      for (int h2 = 0; h2 < 2; ++h2) {
        if (h2) __syncthreads();
#pragma unroll
        for (int nb = 0; nb < 2; ++nb) {
          int ni = 2 * h2 + nb;
          int ld = wc * 32 + nb * 16 + cl;
#pragma unroll
          for (int mi = 0; mi < 4; ++mi)
#pragma unroll
            for (int i = 0; i < 4; ++i) {
              int sl = (wr << 6) + (mi << 4) + rbase + i;
              int o = sl & 31;
              int sp = (sl & ~31) | ((o < 16) ? (o << 1) : (((o - 16) << 1) | 1));
              smem[ld * 136 + sp] = bf16r(acc[mi][ni][i] * wkf[m0 + sl]);
            }
        }
        __syncthreads();
#pragma unroll
        for (int rr = 0; rr < 4; ++rr) {
          int ld = rr * 16 + (t >> 4);
          int cu = (t & 15) * 8;
          int cgo = ((ld >> 5) << 6) + ((2 * h2 + ((ld >> 4) & 1)) << 4) + (ld & 15);
          int cg = n0 + cgo;
          int hh = cg >> 6, d = cg & 63;
          u16x8 val = *(u16x8*)&smem[ld * 136 + cu];
          *(u16x8*)&dst[(((size_t)(bb * 16 + hh)) * 64 + d) * 2048 + s0 + cu] = val;
        }
      }
    }
  } else {
#pragma unroll
    for (int mi = 0; mi < 4; ++mi)
#pragma unroll
      for (int ni = 0; ni < 4; ++ni)
#pragma unroll
        for (int i = 0; i < 4; ++i) {
          int rg = m0 + (wr << 6) + (mi << 4) + rbase + i;
          int cg = n0 + (wc << 6) + (ni << 4) + cl;
          outF[(size_t)rg * 1024 + cg] = acc[mi][ni][i];
        }
  }
}

// ---------------- flash attention chunk (64 kv) ---------------------------
__device__ __forceinline__ void attn_chunk(
    const u16* __restrict__ ksb, const u16* __restrict__ vsb,
    u16* __restrict__ psw, const u16* __restrict__ wkps,
    const u16* __restrict__ poss, int kc, const bf16x8* qa,
    const float* __restrict__ lutf, const int* npq, int pqmin, int pqmax,
    float lut_lo, float lut_hi, int g, int c, f32x4* oacc, f32x4* lacc) {
  f32x4 sc[4];
  __builtin_amdgcn_s_setprio(1);
#pragma unroll
  for (int sub = 0; sub < 4; ++sub) {
    int r = sub * 16 + c;
    f32x4 a = (f32x4){0.f, 0.f, 0.f, 0.f};
#pragma unroll
    for (int kk = 0; kk < 2; ++kk) {
      int cb = ((kk << 6) + (g << 4)) ^ ((r & 7) << 4);
      a = mfma16(qa[kk], ldfrag(ksb + (((r << 7) + cb) >> 1)), a);
    }
    sc[sub] = a;
  }
  __builtin_amdgcn_s_setprio(0);

  int pkmin = (int)poss[kc];
  int pkmax = (int)poss[kc + 63];
  if ((pkmin - pqmax >= 92) || (pqmin - pkmax >= 92)) {
    // whole chunk saturates the bucket -> constant rel bias
    float rbc = (pkmin - pqmax >= 92) ? lut_hi : lut_lo;
#pragma unroll
    for (int sub = 0; sub < 4; ++sub)
#pragma unroll
      for (int i = 0; i < 4; ++i) sc[sub][i] = fast_exp2(sc[sub][i] + rbc);
  } else {
#pragma unroll
    for (int sub = 0; sub < 4; ++sub) {
      int pk = (int)poss[kc + sub * 16 + c];
#pragma unroll
      for (int i = 0; i < 4; ++i) {
        int idx = pk + npq[i];
        idx = idx < 0 ? 0 : (idx > 184 ? 184 : idx);
        sc[sub][i] = fast_exp2(sc[sub][i] + lutf[idx]);
      }
    }
  }
  // pack P pairs (col c, col c+16) -> adjacent slots (2c,2c+1), swizzled
#pragma unroll
  for (int kk = 0; kk < 2; ++kk)
#pragma unroll
    for (int i = 0; i < 4; ++i) {
      int r = g * 4 + i;
      u32 pr;
      asm("v_cvt_pk_bf16_f32 %0, %1, %2"
          : "=v"(pr)
          : "v"(sc[2 * kk][i]), "v"(sc[2 * kk + 1][i]));
      int bo = ((r << 7) + (kk << 6) + (c << 2)) ^ ((r & 7) << 4);
      *(u32*)((char*)psw + bo) = pr;
    }
  // O += P V' ; l += P wk  (wk frag broadcast: same addr for all 16 c-lanes)
  __builtin_amdgcn_s_setprio(1);
#pragma unroll
  for (int kk = 0; kk < 2; ++kk) {
    int bo = ((c << 7) + (kk << 6) + (g << 4)) ^ ((c & 7) << 4);
    bf16x8 pa = __builtin_bit_cast(bf16x8, *(u16x8*)((char*)psw + bo));
    *lacc = mfma16(pa, ldfrag(wkps + kc + kk * 32 + g * 8), *lacc);
#pragma unroll
    for (int d2 = 0; d2 < 4; ++d2) {
      int vr = d2 * 16 + c;
      int vcb = ((kk << 6) + (g << 4)) ^ ((vr & 7) << 4);
      oacc[d2] = mfma16(pa, ldfrag(vsb + (((vr << 7) + vcb) >> 1)), oacc[d2]);
    }
  }
  __builtin_amdgcn_s_setprio(0);
}

// grid (16 qblocks, 32 bh), 8 waves, 16 q-rows/wave, K/V chunks of 64.
__global__ __launch_bounds__(512) void k_attn(
    const u16* __restrict__ qkv, const int* __restrict__ positions,
    const signed char* __restrict__ lut8, const float* __restrict__ rel_emb,
    const u16* __restrict__ wkp, u16* __restrict__ ctx) {
  const int t = threadIdx.x, lane = t & 63, w = t >> 6;
  const int g = lane >> 4, c = lane & 15;
  const int qb = blockIdx.x, bh = blockIdx.y;
  const int b = bh >> 4, h = bh & 15;
  const size_t hb = (size_t)bh * (2048 * 64);
  const u16* Qg = qkv + hb + (size_t)qb * 128 * 64;
  const char* Kg = (const char*)(qkv + (size_t)QKV_MAT_STRIDE + hb);
  const char* Vg = (const char*)(qkv + (size_t)2 * QKV_MAT_STRIDE + hb);

  __shared__ alignas(16) u16 Ks[2][4096], Vs[2][4096];  // dbuf chunks 8KB ea
  __shared__ alignas(16) u16 Ps[8][1024];
  __shared__ alignas(16) u16 poss[2048];
  __shared__ alignas(16) u16 wkps[2048];
  __shared__ float lutf[192];  // bucket bias * log2e for rel in [-92,92]

  if (t < 185) lutf[t] = rel_emb[(int)lut8[t - 92 + 4096] * 16 + h] * LOG2E;
#pragma unroll
  for (int i = 0; i < 4; ++i) {
    poss[i * 512 + t] = (u16)positions[b * 2048 + i * 512 + t];
    wkps[i * 512 + t] = wkp[b * 2048 + i * 512 + t];
  }

  bf16x8 qa[2];
  {
    const u16* qrow = Qg + (size_t)(w * 16 + c) * 64;
    qa[0] = ldfrag(qrow + g * 8);
    qa[1] = ldfrag(qrow + 32 + g * 8);
  }
  const int qrow0 = qb * 128 + w * 16 + g * 4;
  int npq[4];
#pragma unroll
  for (int i = 0; i < 4; ++i) npq[i] = 92 - positions[b * 2048 + qrow0 + i];
  const int pqmin = positions[b * 2048 + qb * 128 + w * 16];
  const int pqmax = positions[b * 2048 + qb * 128 + w * 16 + 15];

  // per-lane staging source (pre-swizzled for linear LDS dest)
  const int so = t << 4;
  const int sr = t >> 3;
  const int scb = (so & 127) ^ ((sr & 7) << 4);
  const char* srcK = Kg + sr * 128 + scb;   // advance 8192 B/chunk
  const char* srcV = Vg + sr * 4096 + scb;  // advance 128 B/chunk

#define STAGE(bi)                                  \
  do {                                             \
    GLOAD16(srcK, (char*)Ks[bi] + w * 1024);       \
    GLOAD16(srcV, (char*)Vs[bi] + w * 1024);       \
    srcK += 8192;                                  \
    srcV += 128;                                   \
  } while (0)

  f32x4 oacc[4];
#pragma unroll
  for (int i = 0; i < 4; ++i) oacc[i] = (f32x4){0.f, 0.f, 0.f, 0.f};
  f32x4 lacc = (f32x4){0.f, 0.f, 0.f, 0.f};

  STAGE(0);
  __syncthreads();
  const float lut_lo = lutf[0], lut_hi = lutf[184];

  int kc = 0;
  for (int t2 = 0; t2 < 16; ++t2) {
    STAGE(1);  // prefetch kc+64 while computing kc
    attn_chunk(Ks[0], Vs[0], &Ps[w][0], wkps, poss, kc, qa, lutf, npq, pqmin,
               pqmax, lut_lo, lut_hi, g, c, oacc, &lacc);
    __syncthreads();
    kc += 64;
    if (t2 < 15) STAGE(0);
    attn_chunk(Ks[1], Vs[1], &Ps[w][0], wkps, poss, kc, qa, lutf, npq, pqmin,
               pqmax, lut_lo, lut_hi, g, c, oacc, &lacc);
    __syncthreads();
    kc += 64;
  }
#undef STAGE

#pragma unroll
  for (int i = 0; i < 4; ++i) {
    float iv = 1.0f / lacc[i];
#pragma unroll
    for (int d2 = 0; d2 < 4; ++d2)
      ctx[((size_t)b * 2048 + qrow0 + i) * 1024 + h * 64 + d2 * 16 + c] =
          bf16r(oacc[d2][i] * iv);
  }
}

// ---------------- launch ----------------
extern "C" void kernel_launch(void* const* d_in, const int* in_sizes, int n_in,
                              void* d_out, int out_size, void* d_ws, size_t ws_size,
                              hipStream_t stream) {
  const float* hs = (const float*)d_in[0];
  const int* pos = (const int*)d_in[1];
  const float* mask = (const float*)d_in[2];
  const float* ss = (const float*)d_in[3];
  const int* nd = (const int*)d_in[4];
  const float* lnw = (const float*)d_in[5];
  const float* Wq = (const float*)d_in[6];
  const float* Wk = (const float*)d_in[7];
  const float* Wv = (const float*)d_in[8];
  const float* Wo = (const float*)d_in[9];
  const float* rel = (const float*)d_in[10];

  char* ws = (char*)d_ws;
  signed char* lut8 = (signed char*)ws;  //          0 .. 8448
  float* wkf = (float*)(ws + 8448);      //       8448 .. 24832
  u16* wkp = (u16*)(ws + 24832);         //      24832 .. 33024
  u16* normed = (u16*)(ws + 33024);      //    33024 + 8 MB (reused as ctx)
  u16* wtqkv = (u16*)(ws + 8421632);     //  + 6 MB
  u16* wto = (u16*)(ws + 14713088);      //  + 2 MB
  u16* qkv = (u16*)(ws + 16810240);      //  + 24 MB  (end 41976064)
  u16* ctx = normed;  // normed is dead after the QKV GEMM
  if (ws_size < 41976064) return;  // loud failure instead of corruption

  k_build_lut<<<33, 256, 0, stream>>>(lut8);
  k_wk<<<16, 256, 0, stream>>>(mask, ss, nd, wkf, wkp);
  k_transpose<<<dim3(32, 32, 4), dim3(32, 8), 0, stream>>>(Wq, Wk, Wv, Wo, wtqkv, wto);
  k_rmsnorm<<<4096, 256, 0, stream>>>(hs, lnw, normed);
  k_gemm<<<dim3(8, 32, 3), 256, 0, stream>>>(normed, wtqkv, qkv, nullptr, wkf, 0);
  k_attn<<<dim3(16, 32), 512, 0, stream>>>(qkv, pos, lut8, rel, wkp, ctx);
  k_gemm<<<dim3(8, 32, 1), 256, 0, stream>>>(ctx, wto, nullptr, (float*)d_out, wkf, 1);
}